// Round 8
// baseline (659.808 us; speedup 1.0000x reference)
//
#include <hip/hip_runtime.h>

#define NEG_SLOPE 0.2f
#define G_SHIFT 8
#define G_SIZE  256      // dst nodes per bucket

typedef __attribute__((ext_vector_type(8))) short short8;
typedef __attribute__((ext_vector_type(4))) float floatx4;

// ---- bf16 helpers (manual RTNE; data is finite) ----
__device__ inline unsigned short f32_to_bf16(float f) {
    union { float f; unsigned int u; } c; c.f = f;
    unsigned int u = c.u;
    u += 0x7FFFu + ((u >> 16) & 1u);
    return (unsigned short)(u >> 16);
}
__device__ inline float bf16_lo(unsigned int u) {
    union { unsigned int u; float f; } c; c.u = u << 16; return c.f;
}
__device__ inline float bf16_hi(unsigned int u) {
    union { unsigned int u; float f; } c; c.u = u & 0xFFFF0000u; return c.f;
}

// ---------------------------------------------------------------------------
// Device-scope grid barrier (R14). bar[0]=count, bar[1]=generation.
// Requirements: all blocks co-resident (grid 391 <= 512 capacity at
// __launch_bounds__(256,2)); state zeroed by the preceding gemm dispatch
// (stream-ordered, so visible). Gen-equality spin; bounded (fails loud,
// never hangs the container). AGENT scope handles cross-XCD coherence.
// ---------------------------------------------------------------------------
__device__ inline void grid_sync(int* bar, int nb) {
    __syncthreads();
    if (threadIdx.x == 0) {
        __threadfence();   // my block's global writes visible device-wide
        int g = __hip_atomic_load(&bar[1], __ATOMIC_ACQUIRE, __HIP_MEMORY_SCOPE_AGENT);
        int a = __hip_atomic_fetch_add(&bar[0], 1, __ATOMIC_ACQ_REL, __HIP_MEMORY_SCOPE_AGENT);
        if (a == nb - 1) {
            __hip_atomic_store(&bar[0], 0, __ATOMIC_RELAXED, __HIP_MEMORY_SCOPE_AGENT);
            __hip_atomic_store(&bar[1], g + 1, __ATOMIC_RELEASE, __HIP_MEMORY_SCOPE_AGENT);
        } else {
            int spins = 0;
            while (__hip_atomic_load(&bar[1], __ATOMIC_ACQUIRE, __HIP_MEMORY_SCOPE_AGENT) == g) {
                __builtin_amdgcn_s_sleep(8);
                if (++spins > (1 << 22)) break;   // ~1s cap: corrupt loudly, don't hang
            }
        }
        __threadfence();
    }
    __syncthreads();
}

// ---------------------------------------------------------------------------
// K1 (R14): fused  W-convert + GEMM + el/er epilogue.
//   - W loaded f32 and converted in-kernel with the SAME RTNE helper ->
//     ftb bit-identical to the wconv path. Removes k_wconv launch.
//   - el/er computed from the f32 accumulators in the epilogue: wave wn owns
//     heads 2wn,2wn+1 entirely (col range wn*64..+63); 4-step shfl_xor
//     width-16 reduce; lane l16==0 writes. Removes k_elr launch + its
//     25.6 MB ftb re-read. (el/er numerics: f32 acc instead of bf16 ft ->
//     closer to reference; the one numeric delta this round.)
//   - A staging: R13 full 8-chunk gl_lds prefetch (validated).
//   - Block 0 zeroes the sort grid-barrier state each run.
// ---------------------------------------------------------------------------
__global__ __launch_bounds__(256) void k_gemm_fused(const float* __restrict__ feat,
                                                    const float* __restrict__ W,
                                                    const float* __restrict__ al,
                                                    const float* __restrict__ ar,
                                                    unsigned short* __restrict__ ftb,
                                                    float* __restrict__ el,
                                                    float* __restrict__ er,
                                                    int* bar,
                                                    int M) {
    __shared__ float Abuf[8][2048];   // 8 chunks x (64 rows x 32 k) f32 = 64 KB

    const int tid  = threadIdx.x;
    const int w    = tid >> 6;        // wave 0..3
    const int lane = tid & 63;
    const int l16  = lane & 15;
    const int quad = lane >> 4;
    const int wm   = w & 1;           // M-half of the 64-row tile
    const int wn   = w >> 1;          // N-half (cols wn*64..wn*64+63)
    const int tile = blockIdx.x * 64;

    if (bar && blockIdx.x == 0 && tid == 0) { bar[0] = 0; bar[1] = 0; }

    // B fragments: load W f32 (L2-hot, 128 KB), convert RTNE -> bf16 frags.
    short8 b[4][8];
#pragma unroll
    for (int t = 0; t < 4; ++t) {
        const float* bp = W + (size_t)((wn * 4 + t) * 16 + l16) * 256 + quad * 8;
#pragma unroll
        for (int kc = 0; kc < 8; ++kc) {
            float4 w0 = *(const float4*)(bp + kc * 32);
            float4 w1 = *(const float4*)(bp + kc * 32 + 4);
            short8 bf;
            bf[0] = (short)f32_to_bf16(w0.x);
            bf[1] = (short)f32_to_bf16(w0.y);
            bf[2] = (short)f32_to_bf16(w0.z);
            bf[3] = (short)f32_to_bf16(w0.w);
            bf[4] = (short)f32_to_bf16(w1.x);
            bf[5] = (short)f32_to_bf16(w1.y);
            bf[6] = (short)f32_to_bf16(w1.z);
            bf[7] = (short)f32_to_bf16(w1.w);
            b[t][kc] = bf;
        }
    }

    // A staging (R13): source-swizzled gl_lds, all 8 chunks in flight.
    const int rloc = lane >> 3;
    const int c4   = ((lane & 7) ^ rloc) * 4;
    int gr0 = tile + (w * 2 + 0) * 8 + rloc; if (gr0 >= M) gr0 = M - 1;
    int gr1 = tile + (w * 2 + 1) * 8 + rloc; if (gr1 >= M) gr1 = M - 1;
    const float* g0 = feat + (size_t)gr0 * 256 + c4;
    const float* g1 = feat + (size_t)gr1 * 256 + c4;

#define STAGE(JC) do {                                                          \
    __builtin_amdgcn_global_load_lds(                                           \
        (const __attribute__((address_space(1))) unsigned int*)(g0 + (JC) * 32),\
        (__attribute__((address_space(3))) unsigned int*)&Abuf[(JC)][(w * 2 + 0) * 256], \
        16, 0, 0);                                                              \
    __builtin_amdgcn_global_load_lds(                                           \
        (const __attribute__((address_space(1))) unsigned int*)(g1 + (JC) * 32),\
        (__attribute__((address_space(3))) unsigned int*)&Abuf[(JC)][(w * 2 + 1) * 256], \
        16, 0, 0);                                                              \
} while (0)

    floatx4 acc[2][4];
#pragma unroll
    for (int m = 0; m < 2; ++m)
#pragma unroll
        for (int t = 0; t < 4; ++t)
            acc[m][t] = (floatx4){0.f, 0.f, 0.f, 0.f};

    STAGE(0); STAGE(1); STAGE(2); STAGE(3);
    STAGE(4); STAGE(5); STAGE(6); STAGE(7);

    const int sw = (l16 & 7) << 4;

#define KSTEP(J, VM) do {                                                       \
    asm volatile("s_waitcnt vmcnt(" #VM ")" ::: "memory");                      \
    __builtin_amdgcn_s_barrier();                                               \
    asm volatile("" ::: "memory");                                              \
    const char* ab = (const char*)&Abuf[(J)][0];                                \
    _Pragma("unroll")                                                           \
    for (int m = 0; m < 2; ++m) {                                               \
        int base = (wm * 32 + m * 16 + l16) * 128 + quad * 32;                  \
        float4 alo = *(const float4*)(ab + ((base)      ^ sw));                 \
        float4 ahi = *(const float4*)(ab + ((base + 16) ^ sw));                 \
        short8 af;                                                              \
        af[0] = (short)f32_to_bf16(alo.x);                                      \
        af[1] = (short)f32_to_bf16(alo.y);                                      \
        af[2] = (short)f32_to_bf16(alo.z);                                      \
        af[3] = (short)f32_to_bf16(alo.w);                                      \
        af[4] = (short)f32_to_bf16(ahi.x);                                      \
        af[5] = (short)f32_to_bf16(ahi.y);                                      \
        af[6] = (short)f32_to_bf16(ahi.z);                                      \
        af[7] = (short)f32_to_bf16(ahi.w);                                      \
        _Pragma("unroll")                                                       \
        for (int t = 0; t < 4; ++t)                                             \
            acc[m][t] = __builtin_amdgcn_mfma_f32_16x16x32_bf16(                \
                af, b[t][(J)], acc[m][t], 0, 0, 0);                             \
    }                                                                           \
} while (0)

    KSTEP(0, 14); KSTEP(1, 12); KSTEP(2, 10); KSTEP(3, 8);
    KSTEP(4,  6); KSTEP(5,  4); KSTEP(6,  2); KSTEP(7, 0);

#undef KSTEP
#undef STAGE

    // C-write (validated mapping: col = l16, rows quad*4+r).
#pragma unroll
    for (int m = 0; m < 2; ++m) {
#pragma unroll
        for (int t = 0; t < 4; ++t) {
#pragma unroll
            for (int r = 0; r < 4; ++r) {
                int row = tile + wm * 32 + m * 16 + quad * 4 + r;
                if (row < M)
                    ftb[(size_t)row * 128 + (wn * 4 + t) * 16 + l16] =
                        f32_to_bf16(acc[m][t][r]);
            }
        }
    }

    // el/er epilogue: head h0 = 2wn (t=0,1), h1 = 2wn+1 (t=2,3).
    const int h0 = wn * 2, h1 = wn * 2 + 1;
    float al00 = al[h0 * 32 + l16],      al01 = al[h0 * 32 + 16 + l16];
    float al10 = al[h1 * 32 + l16],      al11 = al[h1 * 32 + 16 + l16];
    float ar00 = ar[h0 * 32 + l16],      ar01 = ar[h0 * 32 + 16 + l16];
    float ar10 = ar[h1 * 32 + l16],      ar11 = ar[h1 * 32 + 16 + l16];
#pragma unroll
    for (int m = 0; m < 2; ++m) {
#pragma unroll
        for (int r = 0; r < 4; ++r) {
            float p0 = acc[m][0][r] * al00 + acc[m][1][r] * al01;
            float p1 = acc[m][2][r] * al10 + acc[m][3][r] * al11;
            float q0 = acc[m][0][r] * ar00 + acc[m][1][r] * ar01;
            float q1 = acc[m][2][r] * ar10 + acc[m][3][r] * ar11;
#pragma unroll
            for (int d = 1; d < 16; d <<= 1) {
                p0 += __shfl_xor(p0, d, 16);
                p1 += __shfl_xor(p1, d, 16);
                q0 += __shfl_xor(q0, d, 16);
                q1 += __shfl_xor(q1, d, 16);
            }
            if (l16 == 0) {
                int row = tile + wm * 32 + m * 16 + quad * 4 + r;
                if (row < M) {
                    el[row * 4 + h0] = p0;
                    el[row * 4 + h1] = p1;
                    er[row * 4 + h0] = q0;
                    er[row * 4 + h1] = q1;
                }
            }
        }
    }
}

// ---------------------------------------------------------------------------
// K_sort (R14): the ENTIRE R3 sort pipeline in one kernel with grid barriers.
// Grid = B (391) blocks; __launch_bounds__(256,2) -> >=2 blocks/CU -> 512
// co-resident capacity >= 391 (LDS 3 KB, low VGPR). Phases are the proven R3
// kernels with chunk stride B instead of 256. All blocks hit every barrier.
// ---------------------------------------------------------------------------
__global__ __launch_bounds__(256, 2) void k_sort(const int* __restrict__ src,
                                                 const int* __restrict__ dst,
                                                 int* __restrict__ counts,
                                                 int* __restrict__ scanned,
                                                 int* __restrict__ bsum,
                                                 int* __restrict__ part,
                                                 int* __restrict__ offs,
                                                 int* __restrict__ esrc,
                                                 int* bar,
                                                 int E, int B, int CH, int NBs,
                                                 int N, int n2) {
    __shared__ int smA[512];
    __shared__ int smB[256];
    const int j = blockIdx.x, t = threadIdx.x;

    // ---- Phase 1: count (block j = chunk j) ----
    for (int bk = t; bk < B; bk += 256) smA[bk] = 0;
    __syncthreads();
    {
        int lo = j * CH, hi = min(E, lo + CH);
        for (int i = lo + t; i < hi; i += 256)
            atomicAdd(&smA[dst[i] >> G_SHIFT], 1);
    }
    __syncthreads();
    for (int bk = t; bk < B; bk += 256) counts[bk * B + j] = smA[bk];

    grid_sync(bar, B);

    // ---- Phase 2: scan1 (blocks 0..NBs-1, 1024 elems each, out-of-place) ----
    if (j < NBs) {
        int base = j * 1024 + t * 4;
        int d0 = (base + 0 < n2) ? counts[base + 0] : 0;
        int d1 = (base + 1 < n2) ? counts[base + 1] : 0;
        int d2 = (base + 2 < n2) ? counts[base + 2] : 0;
        int d3 = (base + 3 < n2) ? counts[base + 3] : 0;
        int s = d0 + d1 + d2 + d3;
        smA[t] = s;
        __syncthreads();
        for (int o = 1; o < 256; o <<= 1) {
            int v = (t >= o) ? smA[t - o] : 0;
            __syncthreads();
            smA[t] += v;
            __syncthreads();
        }
        int excl = smA[t] - s;
        if (base + 0 < n2) scanned[base + 0] = excl;
        if (base + 1 < n2) scanned[base + 1] = excl + d0;
        if (base + 2 < n2) scanned[base + 2] = excl + d0 + d1;
        if (base + 3 < n2) scanned[base + 3] = excl + d0 + d1 + d2;
        if (t == 255) bsum[j] = smA[255];
    }

    grid_sync(bar, B);

    // ---- Phase 3: scan2 (block 0 scans bsum[NBs], NBs <= 256) ----
    if (j == 0) {
        int v = (t < NBs) ? bsum[t] : 0;
        smA[t] = v;
        __syncthreads();
        for (int o = 1; o < 256; o <<= 1) {
            int u = (t >= o) ? smA[t - o] : 0;
            __syncthreads();
            smA[t] += u;
            __syncthreads();
        }
        if (t < NBs) bsum[t] = smA[t] - v;
    }

    grid_sync(bar, B);

    // ---- Phase 4: partition (block j = chunk j) ----
    for (int bk = t; bk < B; bk += 256) {
        int idx = bk * B + j;
        smA[bk] = scanned[idx] + bsum[idx >> 10];
    }
    __syncthreads();
    {
        int lo = j * CH, hi = min(E, lo + CH);
        for (int i = lo + t; i < hi; i += 256) {
            int d = dst[i];
            int bk = d >> G_SHIFT;
            int pos = atomicAdd(&smA[bk], 1);
            if (pos >= 0 && pos < E)
                part[pos] = ((d & (G_SIZE - 1)) << 17) | src[i];
        }
    }

    grid_sync(bar, B);

    // ---- Phase 5: bucket (block b = bucket b) ----
    {
        const int b = j;
        int i0 = b * B;
        int start = scanned[i0] + bsum[i0 >> 10];
        int end = E;
        if (b < B - 1) {
            int i1 = (b + 1) * B;
            end = scanned[i1] + bsum[i1 >> 10];
        }

        smA[t] = 0;
        __syncthreads();
        for (int i = start + t; i < end; i += 256)
            atomicAdd(&smA[(part[i] >> 17) & 255], 1);
        __syncthreads();

        int h = smA[t];
        __syncthreads();
        for (int o = 1; o < 256; o <<= 1) {
            int v = (t >= o) ? smA[t - o] : 0;
            __syncthreads();
            smA[t] += v;
            __syncthreads();
        }
        int excl = smA[t] - h;
        smB[t] = excl;
        int node = b * G_SIZE + t;
        if (node < N) offs[node] = start + excl;
        if (b == B - 1 && t == 0) offs[N] = E;
        __syncthreads();

        for (int i = start + t; i < end; i += 256) {
            int p = part[i];
            int pos = start + atomicAdd(&smB[(p >> 17) & 255], 1);
            if (pos >= 0 && pos < E) esrc[pos] = p & 0x1FFFF;
        }
    }
}

// ---------------------------------------------------------------------------
// K4 (R3/R8 exact, 75 us): one wave per dst node, 16-edge zero-padded
// passes, all 16 ft gathers in flight; w/s broadcast via ds_bpermute.
// ---------------------------------------------------------------------------
__global__ __launch_bounds__(256) void k_aggr_csr(const int* __restrict__ offs,
                                                  const int* __restrict__ esrc,
                                                  const float* __restrict__ el,
                                                  const float* __restrict__ er,
                                                  const unsigned short* __restrict__ ftb,
                                                  const float* __restrict__ bias,
                                                  float* __restrict__ out,
                                                  int N) {
    int node = blockIdx.x * 4 + (threadIdx.x >> 6);
    if (node >= N) return;
    int lane = threadIdx.x & 63;
    int h1 = lane & 3;
    int h2b = (lane >> 4) << 2;
    float er1 = er[node * 4 + h1];

    int start = offs[node];
    int deg   = offs[node + 1] - start;

    float2 acc = make_float2(0.f, 0.f);
    float  wsum = 0.f;
    const unsigned int* ftu = (const unsigned int*)ftb;

    int p = 0;
    while (p < deg) {
        int cnt = min(16, deg - p);
        float w = 0.f;
        int   s = 0;
        int   e = lane >> 2;
        if (e < cnt) {
            s = esrc[start + p + e];
            float x = el[s * 4 + h1] + er1;
            x = x >= 0.f ? x : NEG_SLOPE * x;
            w = __expf(x);
        }
        float        wv[16];
        unsigned int uv[16];
#pragma unroll
        for (int jj = 0; jj < 16; ++jj) {
            int ib = (jj << 4) + h2b;
            wv[jj] = __int_as_float(
                __builtin_amdgcn_ds_bpermute(ib, __float_as_int(w)));
            int sj = __builtin_amdgcn_ds_bpermute(ib, s);
            uv[jj] = ftu[(size_t)sj * 64 + lane];
        }
#pragma unroll
        for (int jj = 0; jj < 16; ++jj) {
            wsum  += wv[jj];
            acc.x += wv[jj] * bf16_lo(uv[jj]);
            acc.y += wv[jj] * bf16_hi(uv[jj]);
        }
        p += cnt;
    }
    float scale = 1.0f / fmaxf(wsum, 1e-16f);
    float2 bv = ((const float2*)bias)[lane];
    float2 o;
    o.x = acc.x * scale + bv.x;
    o.y = acc.y * scale + bv.y;
    ((float2*)out)[(size_t)node * 64 + lane] = o;
}

// ---------------------------------------------------------------------------
// Fallback (atomic) path — only if ws can't hold sort scratch.
// ---------------------------------------------------------------------------
__global__ __launch_bounds__(256) void k_init_fb(float* __restrict__ out,
                                                 const float* __restrict__ bias,
                                                 float* __restrict__ esum,
                                                 int n_out, int n_esum) {
    int i = blockIdx.x * 256 + threadIdx.x;
    if (i < n_out)  out[i]  = bias[i & 127];
    if (i < n_esum) esum[i] = 0.0f;
}

__global__ __launch_bounds__(256) void k_esum_fb(const int* __restrict__ src,
                                                 const int* __restrict__ dst,
                                                 const float* __restrict__ el,
                                                 const float* __restrict__ er,
                                                 float* __restrict__ esum,
                                                 int E4) {
    int i = blockIdx.x * 256 + threadIdx.x;
    if (i >= E4) return;
    int e = i >> 2, h = i & 3;
    int s = src[e], d = dst[e];
    float x = el[s * 4 + h] + er[d * 4 + h];
    x = x >= 0.f ? x : NEG_SLOPE * x;
    atomicAdd(&esum[d * 4 + h], __expf(x));
}

__global__ __launch_bounds__(256) void k_aggr_fb(const int* __restrict__ src,
                                                 const int* __restrict__ dst,
                                                 const float* __restrict__ el,
                                                 const float* __restrict__ er,
                                                 const float* __restrict__ esum,
                                                 const unsigned short* __restrict__ ftb,
                                                 float* __restrict__ out,
                                                 int E) {
    int i = blockIdx.x * 256 + threadIdx.x;
    int e = i >> 6;
    if (e >= E) return;
    int c = i & 63;
    int h = c >> 4;
    int s = src[e], d = dst[e];
    float x = el[s * 4 + h] + er[d * 4 + h];
    x = x >= 0.f ? x : NEG_SLOPE * x;
    float a = __expf(x) / fmaxf(esum[d * 4 + h], 1e-16f);
    unsigned int u = ((const unsigned int*)ftb)[(size_t)s * 64 + c];
    float* o = out + (size_t)d * 128 + c * 2;
    atomicAdd(o + 0, bf16_lo(u) * a);
    atomicAdd(o + 1, bf16_hi(u) * a);
}

// ---------------------------------------------------------------------------
extern "C" void kernel_launch(void* const* d_in, const int* in_sizes, int n_in,
                              void* d_out, int out_size, void* d_ws, size_t ws_size,
                              hipStream_t stream) {
    const float* feat   = (const float*)d_in[0];
    const int*   src    = (const int*)d_in[1];
    const int*   dst    = (const int*)d_in[2];
    const float* W      = (const float*)d_in[3];
    const float* attn_l = (const float*)d_in[4];
    const float* attn_r = (const float*)d_in[5];
    const float* bias   = (const float*)d_in[6];

    const int N  = in_sizes[0] / 256;   // 100000
    const int E  = in_sizes[1];         // 1600000
    float* out = (float*)d_out;

    const int B   = (N + G_SIZE - 1) / G_SIZE;      // 391 buckets = grid of k_sort
    const int CH  = (E + B - 1) / B;                // edges per chunk
    const int n2  = B * B;                          // count entries
    const int NBs = (n2 + 1023) / 1024;             // scan1 blocks (150 <= 256)

    // ws layout: ftb[N*128 bf16] | el[N*4] | er[N*4] | offs[N+1] |
    //            counts[n2] | scanned[n2] | bsum[256] | bar[8] |
    //            part[E] | esrc[E]
    unsigned short* ftb = (unsigned short*)d_ws;
    float* el = (float*)(ftb + (size_t)N * 128);
    float* er = el + (size_t)N * 4;
    int* offs    = (int*)(er + (size_t)N * 4);
    int* counts  = offs + (N + 1);
    int* scanned = counts + n2;
    int* bsum    = scanned + n2;
    int* bar     = bsum + 256;
    int* part    = bar + 8;
    int* esrc    = part + E;
    size_t need = (size_t)((char*)(esrc + E) - (char*)d_ws);

    const int sorted = (ws_size >= need);

    k_gemm_fused<<<(N + 63) / 64, 256, 0, stream>>>(feat, W, attn_l, attn_r,
                                                    ftb, el, er,
                                                    sorted ? bar : (int*)nullptr, N);

    if (sorted) {
        k_sort<<<B, 256, 0, stream>>>(src, dst, counts, scanned, bsum, part,
                                      offs, esrc, bar, E, B, CH, NBs, N, n2);
        k_aggr_csr<<<(N + 3) / 4, 256, 0, stream>>>(offs, esrc, el, er, ftb,
                                                    bias, out, N);
    } else {
        float* esum = (float*)(er + (size_t)N * 4);
        k_init_fb<<<(N * 128 + 255) / 256, 256, 0, stream>>>(out, bias, esum, N * 128, N * 4);
        k_esum_fb<<<(E * 4 + 255) / 256, 256, 0, stream>>>(src, dst, el, er, esum, E * 4);
        k_aggr_fb<<<((size_t)E * 64 + 255) / 256, 256, 0, stream>>>(src, dst, el, er, esum, ftb, out, E);
    }
}